// Round 6
// baseline (279.033 us; speedup 1.0000x reference)
//
#include <hip/hip_runtime.h>
#include <math.h>

#define HW 16384
#define WID 128
#define BB 4
#define CC 21
#define DD 256
#define NA 84      // BB*CC anchors
#define NV 100
#define NN 8400    // NA*NV
#define NPOS 400   // BB*NV same-class columns per row
#define NPAD 8448  // 66 * 128
#define LDK 72     // LDS row stride (bf16) = 64 + 8 pad
#define NTILE 66   // NPAD/128

typedef __bf16 bf16;
typedef bf16 v8bf __attribute__((ext_vector_type(8)));
typedef float v4f __attribute__((ext_vector_type(4)));

// ---------------- K1: bilinear 2x upsample + argmax over channels ----------
__global__ void pred_kernel(const float* __restrict__ predict, int* __restrict__ pred) {
  int t = blockIdx.x * blockDim.x + threadIdx.x;   // 0..65535
  int b = t / HW;
  int p = t % HW;
  int y = p / WID, x = p % WID;
  float yin = y * 0.5f - 0.25f;
  float xin = x * 0.5f - 0.25f;
  int y0 = (int)floorf(yin), x0 = (int)floorf(xin);
  float fy = yin - (float)y0, fx = xin - (float)x0;
  int y0c = max(y0, 0), y1c = min(y0 + 1, 63);
  int x0c = max(x0, 0), x1c = min(x0 + 1, 63);
  float w00 = (1.f - fy) * (1.f - fx), w01 = (1.f - fy) * fx;
  float w10 = fy * (1.f - fx),        w11 = fy * fx;
  const float* pb = predict + (size_t)b * CC * 4096;
  float best = -1e30f; int bc = 0;
  for (int c = 0; c < CC; ++c) {
    const float* pc = pb + c * 4096;
    float v = w00 * pc[y0c * 64 + x0c] + w01 * pc[y0c * 64 + x1c]
            + w10 * pc[y1c * 64 + x0c] + w11 * pc[y1c * 64 + x1c];
    if (v > best) { best = v; bc = c; }  // strict > keeps first index (jnp.argmax)
  }
  pred[t] = bc;
}

// ---------------- K2: parallel hard/easy index selection -------------------
__global__ __launch_bounds__(256) void select_kernel(const int* __restrict__ pred,
                                                     const int* __restrict__ labels,
                                                     int* __restrict__ idx) {
  int pair = blockIdx.x;         // 0..83
  int b = pair / CC, c = pair % CC;
  int tid = threadIdx.x;         // 0..255
  const int4* pb = (const int4*)(pred + b * HW) + tid * 16;
  const int4* lb = (const int4*)(labels + b * HW) + tid * 16;

  unsigned long long hm = 0ull, em = 0ull;
  #pragma unroll
  for (int g = 0; g < 16; ++g) {
    int4 p4 = pb[g];
    int4 l4 = lb[g];
    unsigned long long h =
        ((unsigned long long)((p4.x == c) & (l4.x != c)))      |
        ((unsigned long long)((p4.y == c) & (l4.y != c)) << 1) |
        ((unsigned long long)((p4.z == c) & (l4.z != c)) << 2) |
        ((unsigned long long)((p4.w == c) & (l4.w != c)) << 3);
    unsigned long long e =
        ((unsigned long long)((p4.x == c) & (l4.x == c)))      |
        ((unsigned long long)((p4.y == c) & (l4.y == c)) << 1) |
        ((unsigned long long)((p4.z == c) & (l4.z == c)) << 2) |
        ((unsigned long long)((p4.w == c) & (l4.w == c)) << 3);
    hm |= h << (g * 4);
    em |= e << (g * 4);
  }
  int nh_t = __popcll(hm), ne_t = __popcll(em);

  __shared__ int sh[256], se[256], ss[256];
  sh[tid] = nh_t; se[tid] = ne_t;
  __syncthreads();
  for (int off = 1; off < 256; off <<= 1) {
    int vh = (tid >= off) ? sh[tid - off] : 0;
    int ve = (tid >= off) ? se[tid - off] : 0;
    __syncthreads();
    sh[tid] += vh; se[tid] += ve;
    __syncthreads();
  }
  int h_excl = sh[tid] - nh_t, e_excl = se[tid] - ne_t;
  int nh = sh[255], ne = se[255];

  const int half = NV / 2;
  int hk;
  if (nh >= half && ne >= half) hk = half;
  else if (nh >= half)          hk = NV - ne;
  else                          hk = nh;
  int ek = NV - hk;

  int takeh = min(max(hk - h_excl, 0), nh_t);
  int takee = min(max(ek - e_excl, 0), ne_t);
  int sel_t = takeh + takee;
  ss[tid] = sel_t;
  __syncthreads();
  for (int off = 1; off < 256; off <<= 1) {
    int vs = (tid >= off) ? ss[tid - off] : 0;
    __syncthreads();
    ss[tid] += vs;
    __syncthreads();
  }
  int s_excl = ss[tid] - sel_t;
  int total_sel = ss[255];
  int F = NV - total_sel;
  int u_excl = tid * 64 - s_excl;

  int* out = idx + pair * NV;
  int sc = 0, uc = 0, hc = 0, ec = 0;
  for (int l = 0; l < 64; ++l) {
    int p = tid * 64 + l;
    int hard = (int)((hm >> l) & 1ull);
    int easy = (int)((em >> l) & 1ull);
    bool sel = (hard && hc < takeh) || (easy && ec < takee);
    hc += hard; ec += easy;
    if (sel) {
      if (s_excl + sc < NV) out[s_excl + sc] = p;
      sc++;
    } else {
      if (u_excl + uc < F) out[total_sel + u_excl + uc] = p;
      uc++;
    }
  }
}

// ---------------- K3: gather selected pixels + L2 normalize -> bf16 --------
__global__ void gather_kernel(const float* __restrict__ feats, const int* __restrict__ idx,
                              bf16* __restrict__ cf) {
  int n = blockIdx.x;            // 0..8399
  int a = n % NA, v = n / NA;
  int b = a / CC;
  int p = idx[a * NV + v];
  int d = threadIdx.x;           // 0..255
  float val = feats[((size_t)(b * DD + d)) * HW + p];
  float ss = val * val;
  for (int o = 32; o; o >>= 1) ss += __shfl_down(ss, o);
  __shared__ float red[4];
  if ((d & 63) == 0) red[d >> 6] = ss;
  __syncthreads();
  float tot = red[0] + red[1] + red[2] + red[3];
  float inv = 1.0f / fmaxf(sqrtf(tot), 1e-12f);
  cf[(size_t)n * DD + d] = (bf16)(val * inv);
}

// ---------------- K4: MFMA bf16 GEMM, full-row exp sums only ---------------
// Full 66x66 grid. Epilogue is pure rowsum += exp(s) over ALL j<NN (pos+self
// included; they are cancelled exactly in loss_kernel via the bit-identical
// pos GEMM). No class logic, no scatter. (R4 post-mortem: scattered s_pos
// epilogue was the regression, not the MFMA.)
__global__ __launch_bounds__(256) void gemm_kernel(const bf16* __restrict__ cf,
                                                   float* __restrict__ row_sum) {
  __shared__ __align__(16) bf16 sA[128 * LDK];
  __shared__ __align__(16) bf16 sB[128 * LDK];
  int i0 = blockIdx.y * 128;
  int j0 = blockIdx.x * 128;
  int tid = threadIdx.x;
  int wave = tid >> 6, lane = tid & 63;
  int wi = wave >> 1, wj = wave & 1;
  int m = lane & 15, q = lane >> 4;

  v4f acc[4][4] = {};

  int srow = tid >> 3;           // 0..31
  int scol = (tid & 7) * 8;      // bf16 col offset, 16B chunks

  for (int k0 = 0; k0 < DD; k0 += 64) {
    #pragma unroll
    for (int rd = 0; rd < 4; ++rd) {
      int r = rd * 32 + srow;
      uint4 va = *(const uint4*)(cf + (size_t)(i0 + r) * DD + k0 + scol);
      uint4 vb = *(const uint4*)(cf + (size_t)(j0 + r) * DD + k0 + scol);
      *(uint4*)(sA + r * LDK + scol) = va;
      *(uint4*)(sB + r * LDK + scol) = vb;
    }
    __syncthreads();
    #pragma unroll
    for (int kk = 0; kk < 2; ++kk) {
      v8bf af[4], bfr[4];
      #pragma unroll
      for (int tt = 0; tt < 4; ++tt)
        af[tt] = *(const v8bf*)(sA + (wi * 64 + tt * 16 + m) * LDK + kk * 32 + q * 8);
      #pragma unroll
      for (int tt = 0; tt < 4; ++tt)
        bfr[tt] = *(const v8bf*)(sB + (wj * 64 + tt * 16 + m) * LDK + kk * 32 + q * 8);
      #pragma unroll
      for (int ti = 0; ti < 4; ++ti)
        #pragma unroll
        for (int tj = 0; tj < 4; ++tj)
          acc[ti][tj] = __builtin_amdgcn_mfma_f32_16x16x32_bf16(af[ti], bfr[tj], acc[ti][tj], 0, 0, 0);
    }
    __syncthreads();
  }

  // ---- epilogue: C/D layout col=lane&15, row=q*4+reg ----
  int iw0 = i0 + wi * 64;
  int jw0 = j0 + wj * 64;

  float rowp[16];
  #pragma unroll
  for (int tt = 0; tt < 16; ++tt) rowp[tt] = 0.f;

  #pragma unroll
  for (int ti = 0; ti < 4; ++ti) {
    #pragma unroll
    for (int r = 0; r < 4; ++r) {
      int i = iw0 + ti * 16 + q * 4 + r;
      if (i >= NN) continue;
      #pragma unroll
      for (int tj = 0; tj < 4; ++tj) {
        int j = jw0 + tj * 16 + m;
        if (j >= NN) continue;
        rowp[ti * 4 + r] += __expf(acc[ti][tj][r] * 10.0f - 10.0f);
      }
    }
  }

  // ---- reduce across the 16 m-lanes, atomic from m==0 lanes ----
  #pragma unroll
  for (int tt = 0; tt < 16; ++tt) {
    float v = rowp[tt];
    v += __shfl_xor(v, 1); v += __shfl_xor(v, 2);
    v += __shfl_xor(v, 4); v += __shfl_xor(v, 8);
    rowp[tt] = v;
  }
  if (m == 0) {
    #pragma unroll
    for (int ti = 0; ti < 4; ++ti)
      #pragma unroll
      for (int r = 0; r < 4; ++r) {
        int i = iw0 + ti * 16 + q * 4 + r;
        if (i < NN) atomicAdd(&row_sum[i], rowp[ti * 4 + r]);
      }
  }
}

// ---------------- K4b: pos GEMM — 21 classes x (512x512 padded) ------------
// Class c rows: i = v*84 + b*21 + c, local rank rr = v*4+b (0..399). Stages
// directly from cf via the row map (pad -> zeroed row NN). Same MFMA K-chain
// as gemm_kernel => bit-identical dots. Coalesced s_pos writes.
__global__ __launch_bounds__(256) void pos_gemm_kernel(const bf16* __restrict__ cf,
                                                       float* __restrict__ s_pos) {
  __shared__ __align__(16) bf16 sA[128 * LDK];
  __shared__ __align__(16) bf16 sB[128 * LDK];
  int c = blockIdx.y;            // 0..20
  int bx = blockIdx.x;           // 0..15
  int i0r = (bx >> 2) * 128;     // local row tile
  int j0r = (bx & 3) * 128;      // local col tile
  int tid = threadIdx.x;
  int wave = tid >> 6, lane = tid & 63;
  int wi = wave >> 1, wj = wave & 1;
  int m = lane & 15, q = lane >> 4;

  v4f acc[4][4] = {};

  int srow = tid >> 3;
  int scol = (tid & 7) * 8;

  for (int k0 = 0; k0 < DD; k0 += 64) {
    #pragma unroll
    for (int rd = 0; rd < 4; ++rd) {
      int r = rd * 32 + srow;
      int ri = i0r + r, rj = j0r + r;
      int gi = (ri < NPOS) ? ((ri >> 2) * NA + (ri & 3) * CC + c) : NN;
      int gj = (rj < NPOS) ? ((rj >> 2) * NA + (rj & 3) * CC + c) : NN;
      uint4 va = *(const uint4*)(cf + (size_t)gi * DD + k0 + scol);
      uint4 vb = *(const uint4*)(cf + (size_t)gj * DD + k0 + scol);
      *(uint4*)(sA + r * LDK + scol) = va;
      *(uint4*)(sB + r * LDK + scol) = vb;
    }
    __syncthreads();
    #pragma unroll
    for (int kk = 0; kk < 2; ++kk) {
      v8bf af[4], bfr[4];
      #pragma unroll
      for (int tt = 0; tt < 4; ++tt)
        af[tt] = *(const v8bf*)(sA + (wi * 64 + tt * 16 + m) * LDK + kk * 32 + q * 8);
      #pragma unroll
      for (int tt = 0; tt < 4; ++tt)
        bfr[tt] = *(const v8bf*)(sB + (wj * 64 + tt * 16 + m) * LDK + kk * 32 + q * 8);
      #pragma unroll
      for (int ti = 0; ti < 4; ++ti)
        #pragma unroll
        for (int tj = 0; tj < 4; ++tj)
          acc[ti][tj] = __builtin_amdgcn_mfma_f32_16x16x32_bf16(af[ti], bfr[tj], acc[ti][tj], 0, 0, 0);
    }
    __syncthreads();
  }

  // epilogue: coalesced stores s_pos[gi][rj]
  #pragma unroll
  for (int ti = 0; ti < 4; ++ti) {
    #pragma unroll
    for (int r = 0; r < 4; ++r) {
      int ri = i0r + wi * 64 + ti * 16 + q * 4 + r;
      if (ri >= NPOS) continue;
      int gi = (ri >> 2) * NA + (ri & 3) * CC + c;
      #pragma unroll
      for (int tj = 0; tj < 4; ++tj) {
        int rj = j0r + wj * 64 + tj * 16 + m;
        if (rj < NPOS)
          s_pos[(size_t)gi * NPOS + rj] = acc[ti][tj][r] * 10.0f - 10.0f;
      }
    }
  }
}

// ---------------- K5: loss — one wave per row ------------------------------
// ns = row_sum[i] - sum_k exp(s_pos[i][k]) (pos+self cancel bit-exactly).
__global__ __launch_bounds__(256) void loss_kernel(const float* __restrict__ s_pos,
                                                   const float* __restrict__ row_sum,
                                                   double* __restrict__ partials) {
  int tid = threadIdx.x;
  int wave = tid >> 6, lane = tid & 63;
  int i = blockIdx.x * 4 + wave;   // 0..8399
  const float* row = s_pos + (size_t)i * NPOS;

  float sp[7], ev[7];
  float psum = 0.f;
  #pragma unroll
  for (int t = 0; t < 7; ++t) {
    int k = lane + t * 64;
    if (k < NPOS) {
      sp[t] = row[k];
      ev[t] = __expf(sp[t]);
      psum += ev[t];
    } else { sp[t] = 0.f; ev[t] = 0.f; }
  }
  for (int o = 32; o; o >>= 1) psum += __shfl_xor(psum, o);
  float ns = row_sum[i] - psum;

  int self = (i / NA) * 4 + ((i % NA) / CC);
  float tsum = 0.f;
  #pragma unroll
  for (int t = 0; t < 7; ++t) {
    int k = lane + t * 64;
    if (k < NPOS && k != self)
      tsum += sp[t] - logf(ev[t] + ns);
  }
  for (int o = 32; o; o >>= 1) tsum += __shfl_xor(tsum, o);

  __shared__ float r2[4];
  if (lane == 0) r2[wave] = tsum;
  __syncthreads();
  if (tid == 0) partials[blockIdx.x] = (double)(r2[0] + r2[1] + r2[2] + r2[3]);
}

__global__ void final_kernel(const double* __restrict__ partials, float* __restrict__ out) {
  int lane = threadIdx.x;        // 64
  double s = 0.0;
  for (int t = lane; t < 2100; t += 64) s += partials[t];
  for (int o = 32; o; o >>= 1) s += __shfl_down(s, o);
  if (lane == 0) out[0] = (float)(-s / 399.0 / 8400.0);
}

// ---------------- launch ---------------------------------------------------
extern "C" void kernel_launch(void* const* d_in, const int* in_sizes, int n_in,
                              void* d_out, int out_size, void* d_ws, size_t ws_size,
                              hipStream_t stream) {
  const float* feats   = (const float*)d_in[0];
  const float* predict = (const float*)d_in[1];
  const int*   labels  = (const int*)d_in[2];
  float* out = (float*)d_out;
  char* ws = (char*)d_ws;

  // workspace layout (bytes)
  int*    pred     = (int*)(ws + 0);          //   262144
  int*    idx      = (int*)(ws + 262144);     //    33600
  float*  row_sum  = (float*)(ws + 295936);   //    33600
  double* partials = (double*)(ws + 329536);  //    16800
  bf16*   cf       = (bf16*)(ws + 346368);    //  4325376 (NPAD*256*2)
  float*  s_pos    = (float*)(ws + 4671744);  // 13440000 (end ~18.1 MB)

  (void)hipMemsetAsync(row_sum, 0, NN * sizeof(float), stream);
  // zero bf16 padding rows 8400..8447 (0x0000 == bf16 zero)
  (void)hipMemsetAsync((char*)(cf + (size_t)NN * DD), 0, (size_t)(NPAD - NN) * DD * 2, stream);

  pred_kernel<<<256, 256, 0, stream>>>(predict, pred);
  select_kernel<<<NA, 256, 0, stream>>>(pred, labels, idx);
  gather_kernel<<<NN, 256, 0, stream>>>(feats, idx, cf);
  gemm_kernel<<<dim3(NTILE, NTILE), 256, 0, stream>>>(cf, row_sum);
  pos_gemm_kernel<<<dim3(16, CC), 256, 0, stream>>>(cf, s_pos);
  loss_kernel<<<2100, 256, 0, stream>>>(s_pos, row_sum, partials);
  final_kernel<<<1, 64, 0, stream>>>(partials, out);
}

// Round 7
// 210.820 us; speedup vs baseline: 1.3236x; 1.3236x over previous
//
#include <hip/hip_runtime.h>
#include <math.h>

#define HW 16384
#define WID 128
#define BB 4
#define CC 21
#define DD 256
#define NA 84      // BB*CC anchors
#define NV 100
#define NN 8400    // NA*NV
#define NPOS 400   // BB*NV same-class columns per row
#define NPAD 8448  // 66 * 128
#define LDK 72     // LDS row stride (bf16) = 64 + 8 pad
#define NTILE 66   // NPAD/128

typedef __bf16 bf16;
typedef bf16 v8bf __attribute__((ext_vector_type(8)));
typedef float v4f __attribute__((ext_vector_type(4)));

// ---------------- K1: bilinear 2x upsample + argmax over channels ----------
__global__ void pred_kernel(const float* __restrict__ predict, int* __restrict__ pred) {
  int t = blockIdx.x * blockDim.x + threadIdx.x;   // 0..65535
  int b = t / HW;
  int p = t % HW;
  int y = p / WID, x = p % WID;
  float yin = y * 0.5f - 0.25f;
  float xin = x * 0.5f - 0.25f;
  int y0 = (int)floorf(yin), x0 = (int)floorf(xin);
  float fy = yin - (float)y0, fx = xin - (float)x0;
  int y0c = max(y0, 0), y1c = min(y0 + 1, 63);
  int x0c = max(x0, 0), x1c = min(x0 + 1, 63);
  float w00 = (1.f - fy) * (1.f - fx), w01 = (1.f - fy) * fx;
  float w10 = fy * (1.f - fx),        w11 = fy * fx;
  const float* pb = predict + (size_t)b * CC * 4096;
  float best = -1e30f; int bc = 0;
  for (int c = 0; c < CC; ++c) {
    const float* pc = pb + c * 4096;
    float v = w00 * pc[y0c * 64 + x0c] + w01 * pc[y0c * 64 + x1c]
            + w10 * pc[y1c * 64 + x0c] + w11 * pc[y1c * 64 + x1c];
    if (v > best) { best = v; bc = c; }  // strict > keeps first index (jnp.argmax)
  }
  pred[t] = bc;
}

// ---------------- K2: parallel hard/easy index selection -------------------
__global__ __launch_bounds__(256) void select_kernel(const int* __restrict__ pred,
                                                     const int* __restrict__ labels,
                                                     int* __restrict__ idx) {
  int pair = blockIdx.x;         // 0..83
  int b = pair / CC, c = pair % CC;
  int tid = threadIdx.x;         // 0..255
  const int4* pb = (const int4*)(pred + b * HW) + tid * 16;
  const int4* lb = (const int4*)(labels + b * HW) + tid * 16;

  unsigned long long hm = 0ull, em = 0ull;
  #pragma unroll
  for (int g = 0; g < 16; ++g) {
    int4 p4 = pb[g];
    int4 l4 = lb[g];
    unsigned long long h =
        ((unsigned long long)((p4.x == c) & (l4.x != c)))      |
        ((unsigned long long)((p4.y == c) & (l4.y != c)) << 1) |
        ((unsigned long long)((p4.z == c) & (l4.z != c)) << 2) |
        ((unsigned long long)((p4.w == c) & (l4.w != c)) << 3);
    unsigned long long e =
        ((unsigned long long)((p4.x == c) & (l4.x == c)))      |
        ((unsigned long long)((p4.y == c) & (l4.y == c)) << 1) |
        ((unsigned long long)((p4.z == c) & (l4.z == c)) << 2) |
        ((unsigned long long)((p4.w == c) & (l4.w == c)) << 3);
    hm |= h << (g * 4);
    em |= e << (g * 4);
  }
  int nh_t = __popcll(hm), ne_t = __popcll(em);

  __shared__ int sh[256], se[256], ss[256];
  sh[tid] = nh_t; se[tid] = ne_t;
  __syncthreads();
  for (int off = 1; off < 256; off <<= 1) {
    int vh = (tid >= off) ? sh[tid - off] : 0;
    int ve = (tid >= off) ? se[tid - off] : 0;
    __syncthreads();
    sh[tid] += vh; se[tid] += ve;
    __syncthreads();
  }
  int h_excl = sh[tid] - nh_t, e_excl = se[tid] - ne_t;
  int nh = sh[255], ne = se[255];

  const int half = NV / 2;
  int hk;
  if (nh >= half && ne >= half) hk = half;
  else if (nh >= half)          hk = NV - ne;
  else                          hk = nh;
  int ek = NV - hk;

  int takeh = min(max(hk - h_excl, 0), nh_t);
  int takee = min(max(ek - e_excl, 0), ne_t);
  int sel_t = takeh + takee;
  ss[tid] = sel_t;
  __syncthreads();
  for (int off = 1; off < 256; off <<= 1) {
    int vs = (tid >= off) ? ss[tid - off] : 0;
    __syncthreads();
    ss[tid] += vs;
    __syncthreads();
  }
  int s_excl = ss[tid] - sel_t;
  int total_sel = ss[255];
  int F = NV - total_sel;
  int u_excl = tid * 64 - s_excl;

  int* out = idx + pair * NV;
  int sc = 0, uc = 0, hc = 0, ec = 0;
  for (int l = 0; l < 64; ++l) {
    int p = tid * 64 + l;
    int hard = (int)((hm >> l) & 1ull);
    int easy = (int)((em >> l) & 1ull);
    bool sel = (hard && hc < takeh) || (easy && ec < takee);
    hc += hard; ec += easy;
    if (sel) {
      if (s_excl + sc < NV) out[s_excl + sc] = p;
      sc++;
    } else {
      if (u_excl + uc < F) out[total_sel + u_excl + uc] = p;
      uc++;
    }
  }
}

// ---------------- K3: gather + L2 normalize -> bf16 ------------------------
// 4 anchors (same (b,c), consecutive v -> spatially clustered sorted pixels)
// per block: one thread per d reads 4 pixels from its 64KB d-row, sharing
// cache lines; 4x fewer line fetches than 1-anchor-per-block.
__global__ __launch_bounds__(256) void gather_kernel(const float* __restrict__ feats,
                                                     const int* __restrict__ idx,
                                                     bf16* __restrict__ cf) {
  int g = blockIdx.x;            // 0..2099
  int a = g % NA;
  int v0 = (g / NA) * 4;
  int b = a / CC;
  int d = threadIdx.x;           // 0..255

  int p[4];
  #pragma unroll
  for (int k = 0; k < 4; ++k) p[k] = idx[a * NV + v0 + k];
  const float* base = feats + (size_t)(b * DD + d) * HW;
  float val[4], ssk[4];
  #pragma unroll
  for (int k = 0; k < 4; ++k) { val[k] = base[p[k]]; ssk[k] = val[k] * val[k]; }

  #pragma unroll
  for (int k = 0; k < 4; ++k) {
    float s = ssk[k];
    s += __shfl_xor(s, 1);  s += __shfl_xor(s, 2);  s += __shfl_xor(s, 4);
    s += __shfl_xor(s, 8);  s += __shfl_xor(s, 16); s += __shfl_xor(s, 32);
    ssk[k] = s;
  }
  __shared__ float red[4][4];
  if ((d & 63) == 0) {
    #pragma unroll
    for (int k = 0; k < 4; ++k) red[d >> 6][k] = ssk[k];
  }
  __syncthreads();
  #pragma unroll
  for (int k = 0; k < 4; ++k) {
    float tot = red[0][k] + red[1][k] + red[2][k] + red[3][k];
    float inv = 1.0f / fmaxf(sqrtf(tot), 1e-12f);
    int n = (v0 + k) * NA + a;
    cf[(size_t)n * DD + d] = (bf16)(val[k] * inv);
  }
}

// ---------------- K4: MFMA bf16 GEMM -> per-block row partials -------------
// Full 66x66 grid; epilogue: exp-rowsum over this block's 128 j-columns,
// cross-lane reduce via LDS (reusing sA after final K-barrier), then ONE
// coalesced 128-float store per block into row_part[jb][i]. ZERO atomics.
// (R6 post-mortem: 4-lane serialized atomic chains were the regression.)
__global__ __launch_bounds__(256) void gemm_kernel(const bf16* __restrict__ cf,
                                                   float* __restrict__ row_part) {
  __shared__ __align__(16) bf16 sA[128 * LDK];
  __shared__ __align__(16) bf16 sB[128 * LDK];
  int i0 = blockIdx.y * 128;
  int j0 = blockIdx.x * 128;
  int tid = threadIdx.x;
  int wave = tid >> 6, lane = tid & 63;
  int wi = wave >> 1, wj = wave & 1;
  int m = lane & 15, q = lane >> 4;

  v4f acc[4][4] = {};

  int srow = tid >> 3;           // 0..31
  int scol = (tid & 7) * 8;      // bf16 col offset, 16B chunks

  for (int k0 = 0; k0 < DD; k0 += 64) {
    #pragma unroll
    for (int rd = 0; rd < 4; ++rd) {
      int r = rd * 32 + srow;
      uint4 va = *(const uint4*)(cf + (size_t)(i0 + r) * DD + k0 + scol);
      uint4 vb = *(const uint4*)(cf + (size_t)(j0 + r) * DD + k0 + scol);
      *(uint4*)(sA + r * LDK + scol) = va;
      *(uint4*)(sB + r * LDK + scol) = vb;
    }
    __syncthreads();
    #pragma unroll
    for (int kk = 0; kk < 2; ++kk) {
      v8bf af[4], bfr[4];
      #pragma unroll
      for (int tt = 0; tt < 4; ++tt)
        af[tt] = *(const v8bf*)(sA + (wi * 64 + tt * 16 + m) * LDK + kk * 32 + q * 8);
      #pragma unroll
      for (int tt = 0; tt < 4; ++tt)
        bfr[tt] = *(const v8bf*)(sB + (wj * 64 + tt * 16 + m) * LDK + kk * 32 + q * 8);
      #pragma unroll
      for (int ti = 0; ti < 4; ++ti)
        #pragma unroll
        for (int tj = 0; tj < 4; ++tj)
          acc[ti][tj] = __builtin_amdgcn_mfma_f32_16x16x32_bf16(af[ti], bfr[tj], acc[ti][tj], 0, 0, 0);
    }
    __syncthreads();
  }

  // ---- epilogue: C/D layout col=lane&15, row=q*4+reg ----
  int jw0 = j0 + wj * 64;

  float rowp[16];
  #pragma unroll
  for (int tt = 0; tt < 16; ++tt) rowp[tt] = 0.f;

  #pragma unroll
  for (int ti = 0; ti < 4; ++ti) {
    #pragma unroll
    for (int r = 0; r < 4; ++r) {
      #pragma unroll
      for (int tj = 0; tj < 4; ++tj) {
        int j = jw0 + tj * 16 + m;
        if (j >= NN) continue;
        rowp[ti * 4 + r] += __expf(acc[ti][tj][r] * 10.0f - 10.0f);
      }
    }
  }

  // ---- cross-lane reduce via LDS (sA reusable after final K-barrier) ----
  float* red = (float*)sA;       // red[128][33]
  #pragma unroll
  for (int ti = 0; ti < 4; ++ti)
    #pragma unroll
    for (int r = 0; r < 4; ++r) {
      int rg = wi * 64 + ti * 16 + q * 4 + r;
      red[rg * 33 + wj * 16 + m] = rowp[ti * 4 + r];
    }
  __syncthreads();
  if (tid < 128) {
    float s = 0.f;
    #pragma unroll
    for (int t = 0; t < 32; ++t) s += red[tid * 33 + t];
    row_part[(size_t)blockIdx.x * NPAD + i0 + tid] = s;  // coalesced, no atomics
  }
}

// ---------------- K4b: pos GEMM — 21 classes x (512x512 padded) ------------
// Class c rows: i = v*84 + b*21 + c, local rank rr = v*4+b (0..399). Stages
// directly from cf via the row map (pad -> zeroed row NN). Same MFMA K-chain
// as gemm_kernel => bit-identical dots. Coalesced s_pos writes.
__global__ __launch_bounds__(256) void pos_gemm_kernel(const bf16* __restrict__ cf,
                                                       float* __restrict__ s_pos) {
  __shared__ __align__(16) bf16 sA[128 * LDK];
  __shared__ __align__(16) bf16 sB[128 * LDK];
  int c = blockIdx.y;            // 0..20
  int bx = blockIdx.x;           // 0..15
  int i0r = (bx >> 2) * 128;     // local row tile
  int j0r = (bx & 3) * 128;      // local col tile
  int tid = threadIdx.x;
  int wave = tid >> 6, lane = tid & 63;
  int wi = wave >> 1, wj = wave & 1;
  int m = lane & 15, q = lane >> 4;

  v4f acc[4][4] = {};

  int srow = tid >> 3;
  int scol = (tid & 7) * 8;

  for (int k0 = 0; k0 < DD; k0 += 64) {
    #pragma unroll
    for (int rd = 0; rd < 4; ++rd) {
      int r = rd * 32 + srow;
      int ri = i0r + r, rj = j0r + r;
      int gi = (ri < NPOS) ? ((ri >> 2) * NA + (ri & 3) * CC + c) : NN;
      int gj = (rj < NPOS) ? ((rj >> 2) * NA + (rj & 3) * CC + c) : NN;
      uint4 va = *(const uint4*)(cf + (size_t)gi * DD + k0 + scol);
      uint4 vb = *(const uint4*)(cf + (size_t)gj * DD + k0 + scol);
      *(uint4*)(sA + r * LDK + scol) = va;
      *(uint4*)(sB + r * LDK + scol) = vb;
    }
    __syncthreads();
    #pragma unroll
    for (int kk = 0; kk < 2; ++kk) {
      v8bf af[4], bfr[4];
      #pragma unroll
      for (int tt = 0; tt < 4; ++tt)
        af[tt] = *(const v8bf*)(sA + (wi * 64 + tt * 16 + m) * LDK + kk * 32 + q * 8);
      #pragma unroll
      for (int tt = 0; tt < 4; ++tt)
        bfr[tt] = *(const v8bf*)(sB + (wj * 64 + tt * 16 + m) * LDK + kk * 32 + q * 8);
      #pragma unroll
      for (int ti = 0; ti < 4; ++ti)
        #pragma unroll
        for (int tj = 0; tj < 4; ++tj)
          acc[ti][tj] = __builtin_amdgcn_mfma_f32_16x16x32_bf16(af[ti], bfr[tj], acc[ti][tj], 0, 0, 0);
    }
    __syncthreads();
  }

  // epilogue: coalesced stores s_pos[gi][rj]
  #pragma unroll
  for (int ti = 0; ti < 4; ++ti) {
    #pragma unroll
    for (int r = 0; r < 4; ++r) {
      int ri = i0r + wi * 64 + ti * 16 + q * 4 + r;
      if (ri >= NPOS) continue;
      int gi = (ri >> 2) * NA + (ri & 3) * CC + c;
      #pragma unroll
      for (int tj = 0; tj < 4; ++tj) {
        int rj = j0r + wj * 64 + tj * 16 + m;
        if (rj < NPOS)
          s_pos[(size_t)gi * NPOS + rj] = acc[ti][tj][r] * 10.0f - 10.0f;
      }
    }
  }
}

// ---------------- K5: loss — one wave per row ------------------------------
// ns = sum_jb row_part[jb][i] - sum_k exp(s_pos[i][k]) (pos+self cancel).
__global__ __launch_bounds__(256) void loss_kernel(const float* __restrict__ s_pos,
                                                   const float* __restrict__ row_part,
                                                   double* __restrict__ partials) {
  int tid = threadIdx.x;
  int wave = tid >> 6, lane = tid & 63;
  int i = blockIdx.x * 4 + wave;   // 0..8399
  const float* row = s_pos + (size_t)i * NPOS;

  float nsum = 0.f;
  for (int jb = lane; jb < NTILE; jb += 64)
    nsum += row_part[(size_t)jb * NPAD + i];

  float sp[7], ev[7];
  float psum = 0.f;
  #pragma unroll
  for (int t = 0; t < 7; ++t) {
    int k = lane + t * 64;
    if (k < NPOS) {
      sp[t] = row[k];
      ev[t] = __expf(sp[t]);
      psum += ev[t];
    } else { sp[t] = 0.f; ev[t] = 0.f; }
  }
  float comb = nsum - psum;
  for (int o = 32; o; o >>= 1) comb += __shfl_xor(comb, o);
  float ns = comb;               // full-row neg sum (butterfly = all-reduce)

  int self = (i / NA) * 4 + ((i % NA) / CC);
  float tsum = 0.f;
  #pragma unroll
  for (int t = 0; t < 7; ++t) {
    int k = lane + t * 64;
    if (k < NPOS && k != self)
      tsum += sp[t] - logf(ev[t] + ns);
  }
  for (int o = 32; o; o >>= 1) tsum += __shfl_xor(tsum, o);

  __shared__ float r2[4];
  if (lane == 0) r2[wave] = tsum;
  __syncthreads();
  if (tid == 0) partials[blockIdx.x] = (double)(r2[0] + r2[1] + r2[2] + r2[3]);
}

__global__ void final_kernel(const double* __restrict__ partials, float* __restrict__ out) {
  int lane = threadIdx.x;        // 64
  double s = 0.0;
  for (int t = lane; t < 2100; t += 64) s += partials[t];
  for (int o = 32; o; o >>= 1) s += __shfl_down(s, o);
  if (lane == 0) out[0] = (float)(-s / 399.0 / 8400.0);
}

// ---------------- launch ---------------------------------------------------
extern "C" void kernel_launch(void* const* d_in, const int* in_sizes, int n_in,
                              void* d_out, int out_size, void* d_ws, size_t ws_size,
                              hipStream_t stream) {
  const float* feats   = (const float*)d_in[0];
  const float* predict = (const float*)d_in[1];
  const int*   labels  = (const int*)d_in[2];
  float* out = (float*)d_out;
  char* ws = (char*)d_ws;

  // workspace layout (bytes)
  int*    pred     = (int*)(ws + 0);           //   262144
  int*    idx      = (int*)(ws + 262144);      //    33600
  float*  row_part = (float*)(ws + 295744);    //  2230272 (66*8448*4)
  double* partials = (double*)(ws + 2526016);  //    16800
  bf16*   cf       = (bf16*)(ws + 2542816);    //  4325376 (NPAD*256*2)
  float*  s_pos    = (float*)(ws + 6868192);   // 13440000 (end ~20.3 MB)

  // zero bf16 padding rows 8400..8447 (0x0000 == bf16 zero)
  (void)hipMemsetAsync((char*)(cf + (size_t)NN * DD), 0, (size_t)(NPAD - NN) * DD * 2, stream);

  pred_kernel<<<256, 256, 0, stream>>>(predict, pred);
  select_kernel<<<NA, 256, 0, stream>>>(pred, labels, idx);
  gather_kernel<<<2100, 256, 0, stream>>>(feats, idx, cf);
  gemm_kernel<<<dim3(NTILE, NTILE), 256, 0, stream>>>(cf, row_part);
  pos_gemm_kernel<<<dim3(16, CC), 256, 0, stream>>>(cf, s_pos);
  loss_kernel<<<2100, 256, 0, stream>>>(s_pos, row_part, partials);
  final_kernel<<<1, 64, 0, stream>>>(partials, out);
}

// Round 8
// 209.742 us; speedup vs baseline: 1.3304x; 1.0051x over previous
//
#include <hip/hip_runtime.h>
#include <math.h>

#define HW 16384
#define WID 128
#define BB 4
#define CC 21
#define DD 256
#define NA 84      // BB*CC anchors
#define NV 100
#define NN 8400    // NA*NV
#define NPOS 400   // BB*NV same-class columns per row
#define NPAD 8448  // 66 * 128
#define NTILE 66   // NPAD/128

typedef __bf16 bf16;
typedef bf16 v8bf __attribute__((ext_vector_type(8)));
typedef float v4f __attribute__((ext_vector_type(4)));

#define AS1(p) ((const __attribute__((address_space(1))) void*)(p))
#define AS3(p) ((__attribute__((address_space(3))) void*)(p))

// ---------------- K1: bilinear 2x upsample + argmax over channels ----------
__global__ void pred_kernel(const float* __restrict__ predict, int* __restrict__ pred) {
  int t = blockIdx.x * blockDim.x + threadIdx.x;   // 0..65535
  int b = t / HW;
  int p = t % HW;
  int y = p / WID, x = p % WID;
  float yin = y * 0.5f - 0.25f;
  float xin = x * 0.5f - 0.25f;
  int y0 = (int)floorf(yin), x0 = (int)floorf(xin);
  float fy = yin - (float)y0, fx = xin - (float)x0;
  int y0c = max(y0, 0), y1c = min(y0 + 1, 63);
  int x0c = max(x0, 0), x1c = min(x0 + 1, 63);
  float w00 = (1.f - fy) * (1.f - fx), w01 = (1.f - fy) * fx;
  float w10 = fy * (1.f - fx),        w11 = fy * fx;
  const float* pb = predict + (size_t)b * CC * 4096;
  float best = -1e30f; int bc = 0;
  for (int c = 0; c < CC; ++c) {
    const float* pc = pb + c * 4096;
    float v = w00 * pc[y0c * 64 + x0c] + w01 * pc[y0c * 64 + x1c]
            + w10 * pc[y1c * 64 + x0c] + w11 * pc[y1c * 64 + x1c];
    if (v > best) { best = v; bc = c; }  // strict > keeps first index (jnp.argmax)
  }
  pred[t] = bc;
}

// ---------------- K2: parallel hard/easy index selection -------------------
__global__ __launch_bounds__(256) void select_kernel(const int* __restrict__ pred,
                                                     const int* __restrict__ labels,
                                                     int* __restrict__ idx) {
  int pair = blockIdx.x;         // 0..83
  int b = pair / CC, c = pair % CC;
  int tid = threadIdx.x;         // 0..255
  const int4* pb = (const int4*)(pred + b * HW) + tid * 16;
  const int4* lb = (const int4*)(labels + b * HW) + tid * 16;

  unsigned long long hm = 0ull, em = 0ull;
  #pragma unroll
  for (int g = 0; g < 16; ++g) {
    int4 p4 = pb[g];
    int4 l4 = lb[g];
    unsigned long long h =
        ((unsigned long long)((p4.x == c) & (l4.x != c)))      |
        ((unsigned long long)((p4.y == c) & (l4.y != c)) << 1) |
        ((unsigned long long)((p4.z == c) & (l4.z != c)) << 2) |
        ((unsigned long long)((p4.w == c) & (l4.w != c)) << 3);
    unsigned long long e =
        ((unsigned long long)((p4.x == c) & (l4.x == c)))      |
        ((unsigned long long)((p4.y == c) & (l4.y == c)) << 1) |
        ((unsigned long long)((p4.z == c) & (l4.z == c)) << 2) |
        ((unsigned long long)((p4.w == c) & (l4.w == c)) << 3);
    hm |= h << (g * 4);
    em |= e << (g * 4);
  }
  int nh_t = __popcll(hm), ne_t = __popcll(em);

  __shared__ int sh[256], se[256], ss[256];
  sh[tid] = nh_t; se[tid] = ne_t;
  __syncthreads();
  for (int off = 1; off < 256; off <<= 1) {
    int vh = (tid >= off) ? sh[tid - off] : 0;
    int ve = (tid >= off) ? se[tid - off] : 0;
    __syncthreads();
    sh[tid] += vh; se[tid] += ve;
    __syncthreads();
  }
  int h_excl = sh[tid] - nh_t, e_excl = se[tid] - ne_t;
  int nh = sh[255], ne = se[255];

  const int half = NV / 2;
  int hk;
  if (nh >= half && ne >= half) hk = half;
  else if (nh >= half)          hk = NV - ne;
  else                          hk = nh;
  int ek = NV - hk;

  int takeh = min(max(hk - h_excl, 0), nh_t);
  int takee = min(max(ek - e_excl, 0), ne_t);
  int sel_t = takeh + takee;
  ss[tid] = sel_t;
  __syncthreads();
  for (int off = 1; off < 256; off <<= 1) {
    int vs = (tid >= off) ? ss[tid - off] : 0;
    __syncthreads();
    ss[tid] += vs;
    __syncthreads();
  }
  int s_excl = ss[tid] - sel_t;
  int total_sel = ss[255];
  int F = NV - total_sel;
  int u_excl = tid * 64 - s_excl;

  int* out = idx + pair * NV;
  int sc = 0, uc = 0, hc = 0, ec = 0;
  for (int l = 0; l < 64; ++l) {
    int p = tid * 64 + l;
    int hard = (int)((hm >> l) & 1ull);
    int easy = (int)((em >> l) & 1ull);
    bool sel = (hard && hc < takeh) || (easy && ec < takee);
    hc += hard; ec += easy;
    if (sel) {
      if (s_excl + sc < NV) out[s_excl + sc] = p;
      sc++;
    } else {
      if (u_excl + uc < F) out[total_sel + u_excl + uc] = p;
      uc++;
    }
  }
}

// ---------------- K3: gather + L2 normalize -> bf16 ------------------------
__global__ __launch_bounds__(256) void gather_kernel(const float* __restrict__ feats,
                                                     const int* __restrict__ idx,
                                                     bf16* __restrict__ cf) {
  int g = blockIdx.x;            // 0..2099
  int a = g % NA;
  int v0 = (g / NA) * 4;
  int b = a / CC;
  int d = threadIdx.x;           // 0..255

  int p[4];
  #pragma unroll
  for (int k = 0; k < 4; ++k) p[k] = idx[a * NV + v0 + k];
  const float* base = feats + (size_t)(b * DD + d) * HW;
  float val[4], ssk[4];
  #pragma unroll
  for (int k = 0; k < 4; ++k) { val[k] = base[p[k]]; ssk[k] = val[k] * val[k]; }

  #pragma unroll
  for (int k = 0; k < 4; ++k) {
    float s = ssk[k];
    s += __shfl_xor(s, 1);  s += __shfl_xor(s, 2);  s += __shfl_xor(s, 4);
    s += __shfl_xor(s, 8);  s += __shfl_xor(s, 16); s += __shfl_xor(s, 32);
    ssk[k] = s;
  }
  __shared__ float red[4][4];
  if ((d & 63) == 0) {
    #pragma unroll
    for (int k = 0; k < 4; ++k) red[d >> 6][k] = ssk[k];
  }
  __syncthreads();
  #pragma unroll
  for (int k = 0; k < 4; ++k) {
    float tot = red[0][k] + red[1][k] + red[2][k] + red[3][k];
    float inv = 1.0f / fmaxf(sqrtf(tot), 1e-12f);
    int n = (v0 + k) * NA + a;
    cf[(size_t)n * DD + d] = (bf16)(val[k] * inv);
  }
}

// ---------------- K4: MFMA bf16 GEMM -> per-block row partials -------------
// Staging via global_load_lds width=16 (direct HBM/L2 -> LDS DMA, no VGPR
// round-trip; m93->m97 = 1.69x on this structure). LDS stride = 64 (the DMA
// scatter is wave-uniform base + lane*16 -> layout must be lane-contiguous;
// padding incompatible). Epilogue: exp-rowsum, LDS reduce, ONE coalesced
// 128-float store per block. Zero atomics.
__global__ __launch_bounds__(256) void gemm_kernel(const bf16* __restrict__ cf,
                                                   float* __restrict__ row_part) {
  __shared__ __align__(16) bf16 smem[2 * 128 * 64];   // sA | sB, 32 KB
  bf16* sA = smem;
  bf16* sB = smem + 128 * 64;
  int i0 = blockIdx.y * 128;
  int j0 = blockIdx.x * 128;
  int tid = threadIdx.x;
  int wave = tid >> 6, lane = tid & 63;
  int wi = wave >> 1, wj = wave & 1;
  int m = lane & 15, q = lane >> 4;

  v4f acc[4][4] = {};

  int lrow = lane >> 3;          // row within 8-row DMA chunk
  int lcol = (lane & 7) * 8;     // bf16 col

  for (int k0 = 0; k0 < DD; k0 += 64) {
    #pragma unroll
    for (int it = 0; it < 4; ++it) {
      int row = wave * 32 + it * 8;               // wave-uniform chunk base
      const bf16* gA = cf + (size_t)(i0 + row + lrow) * DD + k0 + lcol;
      const bf16* gB = cf + (size_t)(j0 + row + lrow) * DD + k0 + lcol;
      __builtin_amdgcn_global_load_lds(AS1(gA), AS3(sA + row * 64), 16, 0, 0);
      __builtin_amdgcn_global_load_lds(AS1(gB), AS3(sB + row * 64), 16, 0, 0);
    }
    __syncthreads();
    #pragma unroll
    for (int kk = 0; kk < 2; ++kk) {
      v8bf af[4], bfr[4];
      #pragma unroll
      for (int tt = 0; tt < 4; ++tt)
        af[tt] = *(const v8bf*)(sA + (wi * 64 + tt * 16 + m) * 64 + kk * 32 + q * 8);
      #pragma unroll
      for (int tt = 0; tt < 4; ++tt)
        bfr[tt] = *(const v8bf*)(sB + (wj * 64 + tt * 16 + m) * 64 + kk * 32 + q * 8);
      #pragma unroll
      for (int ti = 0; ti < 4; ++ti)
        #pragma unroll
        for (int tj = 0; tj < 4; ++tj)
          acc[ti][tj] = __builtin_amdgcn_mfma_f32_16x16x32_bf16(af[ti], bfr[tj], acc[ti][tj], 0, 0, 0);
    }
    __syncthreads();
  }

  // ---- epilogue: C/D layout col=lane&15, row=q*4+reg ----
  int jw0 = j0 + wj * 64;

  float rowp[16];
  #pragma unroll
  for (int tt = 0; tt < 16; ++tt) rowp[tt] = 0.f;

  #pragma unroll
  for (int ti = 0; ti < 4; ++ti) {
    #pragma unroll
    for (int r = 0; r < 4; ++r) {
      #pragma unroll
      for (int tj = 0; tj < 4; ++tj) {
        int j = jw0 + tj * 16 + m;
        if (j >= NN) continue;
        rowp[ti * 4 + r] += __expf(acc[ti][tj][r] * 10.0f - 10.0f);
      }
    }
  }

  // ---- cross-lane reduce via LDS (smem reusable after final K-barrier) ----
  float* red = (float*)smem;     // red[128][33] = 16.9 KB < 32 KB
  #pragma unroll
  for (int ti = 0; ti < 4; ++ti)
    #pragma unroll
    for (int r = 0; r < 4; ++r) {
      int rg = wi * 64 + ti * 16 + q * 4 + r;
      red[rg * 33 + wj * 16 + m] = rowp[ti * 4 + r];
    }
  __syncthreads();
  if (tid < 128) {
    float s = 0.f;
    #pragma unroll
    for (int t = 0; t < 32; ++t) s += red[tid * 33 + t];
    row_part[(size_t)blockIdx.x * NPAD + i0 + tid] = s;  // coalesced, no atomics
  }
}

// ---------------- K4b: pos GEMM — 21 classes x (512x512 padded) ------------
// Class c rows: i = v*84 + b*21 + c, local rank rr = v*4+b (0..399). Stages
// via global_load_lds from the row map (pad -> zeroed row NN). Same MFMA
// K-chain as gemm_kernel => bit-identical dots. Coalesced s_pos writes.
__global__ __launch_bounds__(256) void pos_gemm_kernel(const bf16* __restrict__ cf,
                                                       float* __restrict__ s_pos) {
  __shared__ __align__(16) bf16 smem[2 * 128 * 64];
  bf16* sA = smem;
  bf16* sB = smem + 128 * 64;
  int c = blockIdx.y;            // 0..20
  int bx = blockIdx.x;           // 0..15
  int i0r = (bx >> 2) * 128;     // local row tile
  int j0r = (bx & 3) * 128;      // local col tile
  int tid = threadIdx.x;
  int wave = tid >> 6, lane = tid & 63;
  int wi = wave >> 1, wj = wave & 1;
  int m = lane & 15, q = lane >> 4;

  v4f acc[4][4] = {};

  int lrow = lane >> 3;
  int lcol = (lane & 7) * 8;

  for (int k0 = 0; k0 < DD; k0 += 64) {
    #pragma unroll
    for (int it = 0; it < 4; ++it) {
      int row = wave * 32 + it * 8;
      int ri = i0r + row + lrow, rj = j0r + row + lrow;
      int gi = (ri < NPOS) ? ((ri >> 2) * NA + (ri & 3) * CC + c) : NN;
      int gj = (rj < NPOS) ? ((rj >> 2) * NA + (rj & 3) * CC + c) : NN;
      const bf16* gA = cf + (size_t)gi * DD + k0 + lcol;
      const bf16* gB = cf + (size_t)gj * DD + k0 + lcol;
      __builtin_amdgcn_global_load_lds(AS1(gA), AS3(sA + row * 64), 16, 0, 0);
      __builtin_amdgcn_global_load_lds(AS1(gB), AS3(sB + row * 64), 16, 0, 0);
    }
    __syncthreads();
    #pragma unroll
    for (int kk = 0; kk < 2; ++kk) {
      v8bf af[4], bfr[4];
      #pragma unroll
      for (int tt = 0; tt < 4; ++tt)
        af[tt] = *(const v8bf*)(sA + (wi * 64 + tt * 16 + m) * 64 + kk * 32 + q * 8);
      #pragma unroll
      for (int tt = 0; tt < 4; ++tt)
        bfr[tt] = *(const v8bf*)(sB + (wj * 64 + tt * 16 + m) * 64 + kk * 32 + q * 8);
      #pragma unroll
      for (int ti = 0; ti < 4; ++ti)
        #pragma unroll
        for (int tj = 0; tj < 4; ++tj)
          acc[ti][tj] = __builtin_amdgcn_mfma_f32_16x16x32_bf16(af[ti], bfr[tj], acc[ti][tj], 0, 0, 0);
    }
    __syncthreads();
  }

  // epilogue: coalesced stores s_pos[gi][rj]
  #pragma unroll
  for (int ti = 0; ti < 4; ++ti) {
    #pragma unroll
    for (int r = 0; r < 4; ++r) {
      int ri = i0r + wi * 64 + ti * 16 + q * 4 + r;
      if (ri >= NPOS) continue;
      int gi = (ri >> 2) * NA + (ri & 3) * CC + c;
      #pragma unroll
      for (int tj = 0; tj < 4; ++tj) {
        int rj = j0r + wj * 64 + tj * 16 + m;
        if (rj < NPOS)
          s_pos[(size_t)gi * NPOS + rj] = acc[ti][tj][r] * 10.0f - 10.0f;
      }
    }
  }
}

// ---------------- K5: loss — one wave per row ------------------------------
// ns = sum_jb row_part[jb][i] - sum_k exp(s_pos[i][k]) (pos+self cancel).
__global__ __launch_bounds__(256) void loss_kernel(const float* __restrict__ s_pos,
                                                   const float* __restrict__ row_part,
                                                   double* __restrict__ partials) {
  int tid = threadIdx.x;
  int wave = tid >> 6, lane = tid & 63;
  int i = blockIdx.x * 4 + wave;   // 0..8399
  const float* row = s_pos + (size_t)i * NPOS;

  float nsum = 0.f;
  for (int jb = lane; jb < NTILE; jb += 64)
    nsum += row_part[(size_t)jb * NPAD + i];

  float sp[7], ev[7];
  float psum = 0.f;
  #pragma unroll
  for (int t = 0; t < 7; ++t) {
    int k = lane + t * 64;
    if (k < NPOS) {
      sp[t] = row[k];
      ev[t] = __expf(sp[t]);
      psum += ev[t];
    } else { sp[t] = 0.f; ev[t] = 0.f; }
  }
  float comb = nsum - psum;
  for (int o = 32; o; o >>= 1) comb += __shfl_xor(comb, o);
  float ns = comb;               // full-row neg sum (butterfly = all-reduce)

  int self = (i / NA) * 4 + ((i % NA) / CC);
  float tsum = 0.f;
  #pragma unroll
  for (int t = 0; t < 7; ++t) {
    int k = lane + t * 64;
    if (k < NPOS && k != self)
      tsum += sp[t] - __logf(ev[t] + ns);
  }
  for (int o = 32; o; o >>= 1) tsum += __shfl_xor(tsum, o);

  __shared__ float r2[4];
  if (lane == 0) r2[wave] = tsum;
  __syncthreads();
  if (tid == 0) partials[blockIdx.x] = (double)(r2[0] + r2[1] + r2[2] + r2[3]);
}

__global__ void final_kernel(const double* __restrict__ partials, float* __restrict__ out) {
  int lane = threadIdx.x;        // 64
  double s = 0.0;
  for (int t = lane; t < 2100; t += 64) s += partials[t];
  for (int o = 32; o; o >>= 1) s += __shfl_down(s, o);
  if (lane == 0) out[0] = (float)(-s / 399.0 / 8400.0);
}

// ---------------- launch ---------------------------------------------------
extern "C" void kernel_launch(void* const* d_in, const int* in_sizes, int n_in,
                              void* d_out, int out_size, void* d_ws, size_t ws_size,
                              hipStream_t stream) {
  const float* feats   = (const float*)d_in[0];
  const float* predict = (const float*)d_in[1];
  const int*   labels  = (const int*)d_in[2];
  float* out = (float*)d_out;
  char* ws = (char*)d_ws;

  // workspace layout (bytes)
  int*    pred     = (int*)(ws + 0);           //   262144
  int*    idx      = (int*)(ws + 262144);      //    33600
  float*  row_part = (float*)(ws + 295744);    //  2230272 (66*8448*4)
  double* partials = (double*)(ws + 2526016);  //    16800
  bf16*   cf       = (bf16*)(ws + 2542816);    //  4325376 (NPAD*256*2)
  float*  s_pos    = (float*)(ws + 6868192);   // 13440000 (end ~20.3 MB)

  // zero bf16 padding rows 8400..8447 (0x0000 == bf16 zero)
  (void)hipMemsetAsync((char*)(cf + (size_t)NN * DD), 0, (size_t)(NPAD - NN) * DD * 2, stream);

  pred_kernel<<<256, 256, 0, stream>>>(predict, pred);
  select_kernel<<<NA, 256, 0, stream>>>(pred, labels, idx);
  gather_kernel<<<2100, 256, 0, stream>>>(feats, idx, cf);
  gemm_kernel<<<dim3(NTILE, NTILE), 256, 0, stream>>>(cf, row_part);
  pos_gemm_kernel<<<dim3(16, CC), 256, 0, stream>>>(cf, s_pos);
  loss_kernel<<<2100, 256, 0, stream>>>(s_pos, row_part, partials);
  final_kernel<<<1, 64, 0, stream>>>(partials, out);
}

// Round 9
// 204.807 us; speedup vs baseline: 1.3624x; 1.0241x over previous
//
#include <hip/hip_runtime.h>
#include <math.h>

#define HW 16384
#define WID 128
#define BB 4
#define CC 21
#define DD 256
#define NA 84      // BB*CC anchors
#define NV 100
#define NN 8400    // NA*NV
#define NPOS 400   // BB*NV same-class columns per row
#define NPAD 8448  // 66 * 128
#define NTILE 66   // NPAD/128
#define NSQ (NTILE * NTILE)     // 4356 normal tiles
#define NPOSBLK (16 * CC)       // 336 pos tiles

typedef __bf16 bf16;
typedef bf16 v8bf __attribute__((ext_vector_type(8)));
typedef float v4f __attribute__((ext_vector_type(4)));

#define AS1(p) ((const __attribute__((address_space(1))) void*)(p))
#define AS3(p) ((__attribute__((address_space(3))) void*)(p))

// ---------------- K1: bilinear 2x upsample + argmax over channels ----------
__global__ void pred_kernel(const float* __restrict__ predict, int* __restrict__ pred) {
  int t = blockIdx.x * blockDim.x + threadIdx.x;   // 0..65535
  int b = t / HW;
  int p = t % HW;
  int y = p / WID, x = p % WID;
  float yin = y * 0.5f - 0.25f;
  float xin = x * 0.5f - 0.25f;
  int y0 = (int)floorf(yin), x0 = (int)floorf(xin);
  float fy = yin - (float)y0, fx = xin - (float)x0;
  int y0c = max(y0, 0), y1c = min(y0 + 1, 63);
  int x0c = max(x0, 0), x1c = min(x0 + 1, 63);
  float w00 = (1.f - fy) * (1.f - fx), w01 = (1.f - fy) * fx;
  float w10 = fy * (1.f - fx),        w11 = fy * fx;
  const float* pb = predict + (size_t)b * CC * 4096;
  float best = -1e30f; int bc = 0;
  for (int c = 0; c < CC; ++c) {
    const float* pc = pb + c * 4096;
    float v = w00 * pc[y0c * 64 + x0c] + w01 * pc[y0c * 64 + x1c]
            + w10 * pc[y1c * 64 + x0c] + w11 * pc[y1c * 64 + x1c];
    if (v > best) { best = v; bc = c; }  // strict > keeps first index (jnp.argmax)
  }
  pred[t] = bc;
}

// ---------------- K2: parallel hard/easy index selection -------------------
__global__ __launch_bounds__(256) void select_kernel(const int* __restrict__ pred,
                                                     const int* __restrict__ labels,
                                                     int* __restrict__ idx) {
  int pair = blockIdx.x;         // 0..83
  int b = pair / CC, c = pair % CC;
  int tid = threadIdx.x;         // 0..255
  const int4* pb = (const int4*)(pred + b * HW) + tid * 16;
  const int4* lb = (const int4*)(labels + b * HW) + tid * 16;

  unsigned long long hm = 0ull, em = 0ull;
  #pragma unroll
  for (int g = 0; g < 16; ++g) {
    int4 p4 = pb[g];
    int4 l4 = lb[g];
    unsigned long long h =
        ((unsigned long long)((p4.x == c) & (l4.x != c)))      |
        ((unsigned long long)((p4.y == c) & (l4.y != c)) << 1) |
        ((unsigned long long)((p4.z == c) & (l4.z != c)) << 2) |
        ((unsigned long long)((p4.w == c) & (l4.w != c)) << 3);
    unsigned long long e =
        ((unsigned long long)((p4.x == c) & (l4.x == c)))      |
        ((unsigned long long)((p4.y == c) & (l4.y == c)) << 1) |
        ((unsigned long long)((p4.z == c) & (l4.z == c)) << 2) |
        ((unsigned long long)((p4.w == c) & (l4.w == c)) << 3);
    hm |= h << (g * 4);
    em |= e << (g * 4);
  }
  int nh_t = __popcll(hm), ne_t = __popcll(em);

  __shared__ int sh[256], se[256], ss[256];
  sh[tid] = nh_t; se[tid] = ne_t;
  __syncthreads();
  for (int off = 1; off < 256; off <<= 1) {
    int vh = (tid >= off) ? sh[tid - off] : 0;
    int ve = (tid >= off) ? se[tid - off] : 0;
    __syncthreads();
    sh[tid] += vh; se[tid] += ve;
    __syncthreads();
  }
  int h_excl = sh[tid] - nh_t, e_excl = se[tid] - ne_t;
  int nh = sh[255], ne = se[255];

  const int half = NV / 2;
  int hk;
  if (nh >= half && ne >= half) hk = half;
  else if (nh >= half)          hk = NV - ne;
  else                          hk = nh;
  int ek = NV - hk;

  int takeh = min(max(hk - h_excl, 0), nh_t);
  int takee = min(max(ek - e_excl, 0), ne_t);
  int sel_t = takeh + takee;
  ss[tid] = sel_t;
  __syncthreads();
  for (int off = 1; off < 256; off <<= 1) {
    int vs = (tid >= off) ? ss[tid - off] : 0;
    __syncthreads();
    ss[tid] += vs;
    __syncthreads();
  }
  int s_excl = ss[tid] - sel_t;
  int total_sel = ss[255];
  int F = NV - total_sel;
  int u_excl = tid * 64 - s_excl;

  int* out = idx + pair * NV;
  int sc = 0, uc = 0, hc = 0, ec = 0;
  for (int l = 0; l < 64; ++l) {
    int p = tid * 64 + l;
    int hard = (int)((hm >> l) & 1ull);
    int easy = (int)((em >> l) & 1ull);
    bool sel = (hard && hc < takeh) || (easy && ec < takee);
    hc += hard; ec += easy;
    if (sel) {
      if (s_excl + sc < NV) out[s_excl + sc] = p;
      sc++;
    } else {
      if (u_excl + uc < F) out[total_sel + u_excl + uc] = p;
      uc++;
    }
  }
}

// ---------------- K3: gather + L2 normalize -> bf16 ------------------------
__global__ __launch_bounds__(256) void gather_kernel(const float* __restrict__ feats,
                                                     const int* __restrict__ idx,
                                                     bf16* __restrict__ cf) {
  int g = blockIdx.x;            // 0..2099
  int a = g % NA;
  int v0 = (g / NA) * 4;
  int b = a / CC;
  int d = threadIdx.x;           // 0..255

  int p[4];
  #pragma unroll
  for (int k = 0; k < 4; ++k) p[k] = idx[a * NV + v0 + k];
  const float* base = feats + (size_t)(b * DD + d) * HW;
  float val[4], ssk[4];
  #pragma unroll
  for (int k = 0; k < 4; ++k) { val[k] = base[p[k]]; ssk[k] = val[k] * val[k]; }

  #pragma unroll
  for (int k = 0; k < 4; ++k) {
    float s = ssk[k];
    s += __shfl_xor(s, 1);  s += __shfl_xor(s, 2);  s += __shfl_xor(s, 4);
    s += __shfl_xor(s, 8);  s += __shfl_xor(s, 16); s += __shfl_xor(s, 32);
    ssk[k] = s;
  }
  __shared__ float red[4][4];
  if ((d & 63) == 0) {
    #pragma unroll
    for (int k = 0; k < 4; ++k) red[d >> 6][k] = ssk[k];
  }
  __syncthreads();
  #pragma unroll
  for (int k = 0; k < 4; ++k) {
    float tot = red[0][k] + red[1][k] + red[2][k] + red[3][k];
    float inv = 1.0f / fmaxf(sqrtf(tot), 1e-12f);
    int n = (v0 + k) * NA + a;
    cf[(size_t)n * DD + d] = (bf16)(val[k] * inv);
  }
}

// ---------------- K4: fused MFMA bf16 GEMM (neg rowsums + pos block) -------
// 1-D grid: blocks [0,4356) = full 66x66 neg tiles -> row_part; blocks
// [4356,4692) = 21-class pos tiles -> s_pos (row-mapped staging, same MFMA
// K-chain => bit-identical dots; the serial pos_gemm tail is absorbed).
// Staging: global_load_lds width=16 with XOR-swizzled LDS layout:
// LDS[r][ch] = global chunk ch^(r&7)  (DMA writes lane-contiguous; swizzle
// applied on the lane->global-address side). Read fetches chunk
// (kk*4+q)^(m&7): per quarter-wave each chunk hit by exactly 2 lanes ->
// 2-way = free. (R8: unswizzled stride-64 was a 16-way conflict, 13.9M.)
__global__ __launch_bounds__(256) void gemm_kernel(const bf16* __restrict__ cf,
                                                   float* __restrict__ row_part,
                                                   float* __restrict__ s_pos) {
  __shared__ __align__(16) bf16 smem[2 * 128 * 64];   // sA | sB, 32 KB
  bf16* sA = smem;
  bf16* sB = smem + 128 * 64;
  int blk = blockIdx.x;
  bool pos = blk >= NSQ;
  int i0, j0, c = 0;
  if (!pos) {
    i0 = (blk / NTILE) * 128;
    j0 = (blk % NTILE) * 128;
  } else {
    int pb = blk - NSQ;
    c = pb / 16;
    int bx = pb % 16;
    i0 = (bx >> 2) * 128;        // local row tile within 512
    j0 = (bx & 3) * 128;
  }
  int tid = threadIdx.x;
  int wave = tid >> 6, lane = tid & 63;
  int wi = wave >> 1, wj = wave & 1;
  int m = lane & 15, q = lane >> 4;

  v4f acc[4][4] = {};

  int lrow = lane >> 3;          // 0..7: row within 8-row DMA chunk
  int cxor = (lane & 7) ^ lrow;  // swizzled global 16B-chunk index

  for (int k0 = 0; k0 < DD; k0 += 64) {
    #pragma unroll
    for (int it = 0; it < 4; ++it) {
      int row = wave * 32 + it * 8;               // wave-uniform chunk base
      int ri = i0 + row + lrow, rj = j0 + row + lrow;
      int gi, gj;
      if (!pos) { gi = ri; gj = rj; }
      else {
        gi = (ri < NPOS) ? ((ri >> 2) * NA + (ri & 3) * CC + c) : NN;
        gj = (rj < NPOS) ? ((rj >> 2) * NA + (rj & 3) * CC + c) : NN;
      }
      const bf16* gA = cf + (size_t)gi * DD + k0 + cxor * 8;
      const bf16* gB = cf + (size_t)gj * DD + k0 + cxor * 8;
      __builtin_amdgcn_global_load_lds(AS1(gA), AS3(sA + row * 64), 16, 0, 0);
      __builtin_amdgcn_global_load_lds(AS1(gB), AS3(sB + row * 64), 16, 0, 0);
    }
    __syncthreads();
    #pragma unroll
    for (int kk = 0; kk < 2; ++kk) {
      v8bf af[4], bfr[4];
      #pragma unroll
      for (int tt = 0; tt < 4; ++tt) {
        int r = wi * 64 + tt * 16 + m;
        af[tt] = *(const v8bf*)(sA + r * 64 + (((kk * 4 + q) ^ (m & 7)) * 8));
      }
      #pragma unroll
      for (int tt = 0; tt < 4; ++tt) {
        int r = wj * 64 + tt * 16 + m;
        bfr[tt] = *(const v8bf*)(sB + r * 64 + (((kk * 4 + q) ^ (m & 7)) * 8));
      }
      #pragma unroll
      for (int ti = 0; ti < 4; ++ti)
        #pragma unroll
        for (int tj = 0; tj < 4; ++tj)
          acc[ti][tj] = __builtin_amdgcn_mfma_f32_16x16x32_bf16(af[ti], bfr[tj], acc[ti][tj], 0, 0, 0);
    }
    __syncthreads();
  }

  // ---- epilogue: C/D layout col=lane&15, row=q*4+reg ----
  if (!pos) {
    int jw0 = j0 + wj * 64;
    float rowp[16];
    #pragma unroll
    for (int tt = 0; tt < 16; ++tt) rowp[tt] = 0.f;

    #pragma unroll
    for (int ti = 0; ti < 4; ++ti) {
      #pragma unroll
      for (int r = 0; r < 4; ++r) {
        #pragma unroll
        for (int tj = 0; tj < 4; ++tj) {
          int j = jw0 + tj * 16 + m;
          if (j >= NN) continue;
          rowp[ti * 4 + r] += __expf(acc[ti][tj][r] * 10.0f - 10.0f);
        }
      }
    }

    // cross-lane reduce via LDS (smem reusable after final K-barrier)
    float* red = (float*)smem;   // red[128][33] = 16.9 KB < 32 KB
    #pragma unroll
    for (int ti = 0; ti < 4; ++ti)
      #pragma unroll
      for (int r = 0; r < 4; ++r) {
        int rg = wi * 64 + ti * 16 + q * 4 + r;
        red[rg * 33 + wj * 16 + m] = rowp[ti * 4 + r];
      }
    __syncthreads();
    if (tid < 128) {
      float s = 0.f;
      #pragma unroll
      for (int t = 0; t < 32; ++t) s += red[tid * 33 + t];
      row_part[(size_t)(blk % NTILE) * NPAD + i0 + tid] = s;  // coalesced
    }
  } else {
    #pragma unroll
    for (int ti = 0; ti < 4; ++ti) {
      #pragma unroll
      for (int r = 0; r < 4; ++r) {
        int ri = i0 + wi * 64 + ti * 16 + q * 4 + r;
        if (ri >= NPOS) continue;
        int gi = (ri >> 2) * NA + (ri & 3) * CC + c;
        #pragma unroll
        for (int tj = 0; tj < 4; ++tj) {
          int rj = j0 + wj * 64 + tj * 16 + m;
          if (rj < NPOS)
            s_pos[(size_t)gi * NPOS + rj] = acc[ti][tj][r] * 10.0f - 10.0f;
        }
      }
    }
  }
}

// ---------------- K5: loss — one wave per row ------------------------------
// ns = sum_jb row_part[jb][i] - sum_k exp(s_pos[i][k]) (pos+self cancel).
__global__ __launch_bounds__(256) void loss_kernel(const float* __restrict__ s_pos,
                                                   const float* __restrict__ row_part,
                                                   double* __restrict__ partials) {
  int tid = threadIdx.x;
  int wave = tid >> 6, lane = tid & 63;
  int i = blockIdx.x * 4 + wave;   // 0..8399
  const float* row = s_pos + (size_t)i * NPOS;

  float nsum = 0.f;
  for (int jb = lane; jb < NTILE; jb += 64)
    nsum += row_part[(size_t)jb * NPAD + i];

  float sp[7], ev[7];
  float psum = 0.f;
  #pragma unroll
  for (int t = 0; t < 7; ++t) {
    int k = lane + t * 64;
    if (k < NPOS) {
      sp[t] = row[k];
      ev[t] = __expf(sp[t]);
      psum += ev[t];
    } else { sp[t] = 0.f; ev[t] = 0.f; }
  }
  float comb = nsum - psum;
  for (int o = 32; o; o >>= 1) comb += __shfl_xor(comb, o);
  float ns = comb;               // full-row neg sum (butterfly = all-reduce)

  int self = (i / NA) * 4 + ((i % NA) / CC);
  float tsum = 0.f;
  #pragma unroll
  for (int t = 0; t < 7; ++t) {
    int k = lane + t * 64;
    if (k < NPOS && k != self)
      tsum += sp[t] - __logf(ev[t] + ns);
  }
  for (int o = 32; o; o >>= 1) tsum += __shfl_xor(tsum, o);

  __shared__ float r2[4];
  if (lane == 0) r2[wave] = tsum;
  __syncthreads();
  if (tid == 0) partials[blockIdx.x] = (double)(r2[0] + r2[1] + r2[2] + r2[3]);
}

__global__ void final_kernel(const double* __restrict__ partials, float* __restrict__ out) {
  int lane = threadIdx.x;        // 64
  double s = 0.0;
  for (int t = lane; t < 2100; t += 64) s += partials[t];
  for (int o = 32; o; o >>= 1) s += __shfl_down(s, o);
  if (lane == 0) out[0] = (float)(-s / 399.0 / 8400.0);
}

// ---------------- launch ---------------------------------------------------
extern "C" void kernel_launch(void* const* d_in, const int* in_sizes, int n_in,
                              void* d_out, int out_size, void* d_ws, size_t ws_size,
                              hipStream_t stream) {
  const float* feats   = (const float*)d_in[0];
  const float* predict = (const float*)d_in[1];
  const int*   labels  = (const int*)d_in[2];
  float* out = (float*)d_out;
  char* ws = (char*)d_ws;

  // workspace layout (bytes)
  int*    pred     = (int*)(ws + 0);           //   262144
  int*    idx      = (int*)(ws + 262144);      //    33600
  float*  row_part = (float*)(ws + 295744);    //  2230272 (66*8448*4)
  double* partials = (double*)(ws + 2526016);  //    16800
  bf16*   cf       = (bf16*)(ws + 2542816);    //  4325376 (NPAD*256*2)
  float*  s_pos    = (float*)(ws + 6868192);   // 13440000 (end ~20.3 MB)

  // zero bf16 padding rows 8400..8447 (0x0000 == bf16 zero)
  (void)hipMemsetAsync((char*)(cf + (size_t)NN * DD), 0, (size_t)(NPAD - NN) * DD * 2, stream);

  pred_kernel<<<256, 256, 0, stream>>>(predict, pred);
  select_kernel<<<NA, 256, 0, stream>>>(pred, labels, idx);
  gather_kernel<<<2100, 256, 0, stream>>>(feats, idx, cf);
  gemm_kernel<<<NSQ + NPOSBLK, 256, 0, stream>>>(cf, row_part, s_pos);
  loss_kernel<<<2100, 256, 0, stream>>>(s_pos, row_part, partials);
  final_kernel<<<1, 64, 0, stream>>>(partials, out);
}